// Round 3
// baseline (788.872 us; speedup 1.0000x reference)
//
#include <hip/hip_runtime.h>
#include <math.h>

constexpr int H    = 32;
constexpr int HKV  = 8;
constexpr int GQ   = 4;      // H / HKV
constexpr int D    = 128;
constexpr int HID  = 4096;
constexpr int INTD = 12288;
constexpr int S    = 8192;
constexpr float EPS   = 1e-6f;
constexpr float SCALE = 0.088388347648318447f; // 1/sqrt(128)
constexpr int NCHUNK = 128;      // split-K chunks per kv-head
constexpr int CH     = S / NCHUNK; // 64

__device__ __forceinline__ float wave_red_sum(float v) {
#pragma unroll
    for (int o = 32; o > 0; o >>= 1) v += __shfl_down(v, o, 64);
    return v;
}

// ---------------- 1,7: RMSNorm over HID=4096 (1 block, 1024 threads) ----------------
__global__ __launch_bounds__(1024) void rmsnorm_k(const float* __restrict__ x,
                                                  const float* __restrict__ w,
                                                  float* __restrict__ out) {
    __shared__ float red[16];
    __shared__ float sinv;
    int t = threadIdx.x;
    float4 v = reinterpret_cast<const float4*>(x)[t];
    float ss = v.x * v.x + v.y * v.y + v.z * v.z + v.w * v.w;
    ss = wave_red_sum(ss);
    if ((t & 63) == 0) red[t >> 6] = ss;
    __syncthreads();
    if (t == 0) {
        float tot = 0.f;
#pragma unroll
        for (int i = 0; i < 16; ++i) tot += red[i];
        sinv = rsqrtf(tot / (float)HID + EPS);
    }
    __syncthreads();
    float s = sinv;
    float4 wv = reinterpret_cast<const float4*>(w)[t];
    float4 o;
    o.x = v.x * s * wv.x; o.y = v.y * s * wv.y;
    o.z = v.z * s * wv.z; o.w = v.w * s * wv.w;
    reinterpret_cast<float4*>(out)[t] = o;
}

// ---------------- 2: fused QKV GEMV. rows: [0,4096)=Q, [4096,5120)=K, [5120,6144)=V ----
__global__ __launch_bounds__(256) void qkv_k(const float* __restrict__ Wq,
                                             const float* __restrict__ Wk,
                                             const float* __restrict__ Wv,
                                             const float* __restrict__ h,
                                             float* __restrict__ q,
                                             float* __restrict__ kn,
                                             float* __restrict__ vn) {
    int r = blockIdx.x;
    int t = threadIdx.x;
    const float* W;
    float* out;
    int row;
    if (r < H * D)            { W = Wq; row = r;                 out = q  + row; }
    else if (r < H*D + HKV*D) { W = Wk; row = r - H*D;           out = kn + row; }
    else                      { W = Wv; row = r - H*D - HKV*D;   out = vn + row; }
    const float4* Wr = reinterpret_cast<const float4*>(W + (size_t)row * HID);
    const float4* hv = reinterpret_cast<const float4*>(h);
    float acc = 0.f;
#pragma unroll
    for (int it = 0; it < HID / (4 * 256); ++it) { // 4 iters
        float4 a = Wr[t + it * 256];
        float4 b = hv[t + it * 256];
        acc += a.x * b.x + a.y * b.y + a.z * b.z + a.w * b.w;
    }
    acc = wave_red_sum(acc);
    __shared__ float red[4];
    if ((t & 63) == 0) red[t >> 6] = acc;
    __syncthreads();
    if (t == 0) *out = red[0] + red[1] + red[2] + red[3];
}

// ---------------- 3: per-head RMSNorm + RoPE; scatter k,v into cache ----------------
// blocks 0..31 = q heads, blocks 32..39 = kv heads. 128 threads.
__global__ __launch_bounds__(128) void norm_rope_k(float* __restrict__ q,
                                                   const float* __restrict__ kn,
                                                   const float* __restrict__ vn,
                                                   const float* __restrict__ qw,
                                                   const float* __restrict__ kw,
                                                   const float* __restrict__ cosv,
                                                   const float* __restrict__ sinv_,
                                                   const int* __restrict__ pos_p,
                                                   float* __restrict__ kv_cache) {
    int b = blockIdx.x, d = threadIdx.x;
    __shared__ float xw[D];
    __shared__ float red2[2];
    __shared__ float sinv;
    float x;
    const float* w;
    if (b < H) { x = q[b * D + d];        w = qw; }
    else       { x = kn[(b - H) * D + d]; w = kw; }
    float ss = x * x;
    ss = wave_red_sum(ss);
    if ((d & 63) == 0) red2[d >> 6] = ss;
    __syncthreads();
    if (d == 0) sinv = rsqrtf((red2[0] + red2[1]) / (float)D + EPS);
    __syncthreads();
    float xn = x * sinv * w[d];
    xw[d] = xn;
    __syncthreads();
    int   p    = (d < 64) ? d + 64 : d - 64;
    float sign = (d < 64) ? -1.f : 1.f;
    float o = xn * cosv[d] + sign * xw[p] * sinv_[d];
    if (b < H) {
        q[b * D + d] = o;
    } else {
        int g = b - H;
        int pos = *pos_p;
        kv_cache[((size_t)g * S + pos) * D + d] = o;                       // K plane
        kv_cache[((size_t)(HKV + g) * S + pos) * D + d] = vn[g * D + d];   // V plane
    }
}

// ---------------- 4: flash split-K attention. grid = HKV*NCHUNK, 256 thr (4 waves) ---
__global__ __launch_bounds__(256) void attn_split_k(const float* __restrict__ q,
                                                    const float* __restrict__ kv,
                                                    const float* __restrict__ mask,
                                                    float* __restrict__ part_m,
                                                    float* __restrict__ part_l,
                                                    float* __restrict__ part_o) {
    int g     = blockIdx.x / NCHUNK;
    int chunk = blockIdx.x % NCHUNK;
    int t = threadIdx.x;
    int wave = t >> 6, lane = t & 63;
    const float* K = kv + (size_t)g * S * D;
    const float* V = kv + (size_t)(HKV + g) * S * D;

    float2 qh[GQ];
#pragma unroll
    for (int h = 0; h < GQ; ++h) {
        qh[h] = *reinterpret_cast<const float2*>(q + (size_t)(g * GQ + h) * D + 2 * lane);
        qh[h].x *= SCALE; qh[h].y *= SCALE;   // fold 1/sqrt(D) into q
    }

    float m[GQ], l[GQ];
    float2 o[GQ];
#pragma unroll
    for (int h = 0; h < GQ; ++h) { m[h] = -INFINITY; l[h] = 0.f; o[h].x = 0.f; o[h].y = 0.f; }

    int s0 = chunk * CH;
    // unroll 2: two rows' K/V/mask loads issue before the dependent shuffle
    // chains, doubling outstanding memory per wave (latency cover ~1200 cyc).
#pragma unroll 2
    for (int s = s0 + wave; s < s0 + CH; s += 4) {
        float2 kk = *reinterpret_cast<const float2*>(K + (size_t)s * D + 2 * lane);
        float2 vv = *reinterpret_cast<const float2*>(V + (size_t)s * D + 2 * lane);
        float mk = mask[s];
        float p0 = qh[0].x * kk.x + qh[0].y * kk.y;
        float p1 = qh[1].x * kk.x + qh[1].y * kk.y;
        float p2 = qh[2].x * kk.x + qh[2].y * kk.y;
        float p3 = qh[3].x * kk.x + qh[3].y * kk.y;
#pragma unroll
        for (int off = 32; off > 0; off >>= 1) {
            p0 += __shfl_xor(p0, off, 64);
            p1 += __shfl_xor(p1, off, 64);
            p2 += __shfl_xor(p2, off, 64);
            p3 += __shfl_xor(p3, off, 64);
        }
        float sc[GQ] = { p0 + mk, p1 + mk, p2 + mk, p3 + mk };
#pragma unroll
        for (int h = 0; h < GQ; ++h) {
            float mn = fmaxf(m[h], sc[h]);
            float c  = __expf(m[h] - mn);
            float p  = __expf(sc[h] - mn);
            l[h] = l[h] * c + p;
            o[h].x = o[h].x * c + p * vv.x;
            o[h].y = o[h].y * c + p * vv.y;
            m[h] = mn;
        }
    }

    // merge 4 waves via LDS; wave w then owns head h==w
    __shared__ float lm[4][GQ], ll[4][GQ];
    __shared__ float lo[4][GQ][D];
#pragma unroll
    for (int h = 0; h < GQ; ++h) {
        if (lane == 0) { lm[wave][h] = m[h]; ll[wave][h] = l[h]; }
        lo[wave][h][2 * lane]     = o[h].x;
        lo[wave][h][2 * lane + 1] = o[h].y;
    }
    __syncthreads();
    int h = wave;
    float M = fmaxf(fmaxf(lm[0][h], lm[1][h]), fmaxf(lm[2][h], lm[3][h]));
    float L = 0.f;
    float2 oo = { 0.f, 0.f };
#pragma unroll
    for (int w2 = 0; w2 < 4; ++w2) {
        float e = __expf(lm[w2][h] - M);
        L   += ll[w2][h] * e;
        oo.x += lo[w2][h][2 * lane]     * e;
        oo.y += lo[w2][h][2 * lane + 1] * e;
    }
    int idx = blockIdx.x * GQ + h;   // (g*NCHUNK+chunk)*GQ + h
    if (lane == 0) { part_m[idx] = M; part_l[idx] = L; }
    *reinterpret_cast<float2*>(part_o + (size_t)idx * D + 2 * lane) = oo;
}

// ---------------- 5: combine NCHUNK partials per q-head. grid = 32, 128 thr --------
__global__ __launch_bounds__(128) void attn_combine_k(const float* __restrict__ part_m,
                                                      const float* __restrict__ part_l,
                                                      const float* __restrict__ part_o,
                                                      float* __restrict__ out) {
    int qh = blockIdx.x;
    int g = qh / GQ, h = qh % GQ;
    int t = threadIdx.x;           // 0..127: chunk index, then d index
    int idx = (g * NCHUNK + t) * GQ + h;
    float mc = part_m[idx], lc = part_l[idx];
    float M = mc;
#pragma unroll
    for (int off = 32; off > 0; off >>= 1) M = fmaxf(M, __shfl_xor(M, off, 64));
    __shared__ float sm[2], sl[2];
    __shared__ float es[NCHUNK];
    if ((t & 63) == 0) sm[t >> 6] = M;
    __syncthreads();
    M = fmaxf(sm[0], sm[1]);
    float e = __expf(mc - M);
    es[t] = e;
    float L = lc * e;
#pragma unroll
    for (int off = 32; off > 0; off >>= 1) L += __shfl_xor(L, off, 64);
    if ((t & 63) == 0) sl[t >> 6] = L;
    __syncthreads();
    L = sl[0] + sl[1];
    // thread t now covers output dim d = t
    float acc = 0.f;
#pragma unroll 8
    for (int c = 0; c < NCHUNK; ++c)
        acc += part_o[(size_t)((g * NCHUNK + c) * GQ + h) * D + t] * es[c];
    out[qh * D + t] = acc / L;
}

// ---------------- 6: Wo GEMV + residual ----------------
__global__ __launch_bounds__(256) void gemv_wo_k(const float* __restrict__ Wo,
                                                 const float* __restrict__ ao,
                                                 const float* __restrict__ x,
                                                 float* __restrict__ hidden) {
    int r = blockIdx.x, t = threadIdx.x;
    const float4* Wr = reinterpret_cast<const float4*>(Wo + (size_t)r * HID);
    const float4* av = reinterpret_cast<const float4*>(ao);
    float acc = 0.f;
#pragma unroll
    for (int it = 0; it < HID / (4 * 256); ++it) {
        float4 a = Wr[t + it * 256];
        float4 b = av[t + it * 256];
        acc += a.x * b.x + a.y * b.y + a.z * b.z + a.w * b.w;
    }
    acc = wave_red_sum(acc);
    __shared__ float red[4];
    if ((t & 63) == 0) red[t >> 6] = acc;
    __syncthreads();
    if (t == 0) hidden[r] = x[r] + red[0] + red[1] + red[2] + red[3];
}

// ---------------- 8: Wgu GEMV + silu(gate)*up ----------------
__global__ __launch_bounds__(256) void gemv_gu_k(const float* __restrict__ Wgu,
                                                 const float* __restrict__ h2,
                                                 float* __restrict__ act) {
    int r = blockIdx.x, t = threadIdx.x;
    const float4* Wg = reinterpret_cast<const float4*>(Wgu + (size_t)r * HID);
    const float4* Wu = reinterpret_cast<const float4*>(Wgu + (size_t)(r + INTD) * HID);
    const float4* hv = reinterpret_cast<const float4*>(h2);
    float ag = 0.f, au = 0.f;
#pragma unroll
    for (int it = 0; it < HID / (4 * 256); ++it) {
        float4 b = hv[t + it * 256];
        float4 a = Wg[t + it * 256];
        float4 u = Wu[t + it * 256];
        ag += a.x * b.x + a.y * b.y + a.z * b.z + a.w * b.w;
        au += u.x * b.x + u.y * b.y + u.z * b.z + u.w * b.w;
    }
    ag = wave_red_sum(ag);
    au = wave_red_sum(au);
    __shared__ float rg[4], ru[4];
    if ((t & 63) == 0) { rg[t >> 6] = ag; ru[t >> 6] = au; }
    __syncthreads();
    if (t == 0) {
        float gg = rg[0] + rg[1] + rg[2] + rg[3];
        float uu = ru[0] + ru[1] + ru[2] + ru[3];
        act[r] = gg / (1.f + __expf(-gg)) * uu;   // silu(g)*u
    }
}

// ---------------- 9: Wd GEMV + residual -> out ----------------
__global__ __launch_bounds__(256) void gemv_wd_k(const float* __restrict__ Wd,
                                                 const float* __restrict__ act,
                                                 const float* __restrict__ hidden,
                                                 float* __restrict__ out) {
    int r = blockIdx.x, t = threadIdx.x;
    const float4* Wr = reinterpret_cast<const float4*>(Wd + (size_t)r * INTD);
    const float4* av = reinterpret_cast<const float4*>(act);
    float acc = 0.f;
#pragma unroll
    for (int it = 0; it < INTD / (4 * 256); ++it) { // 12 iters
        float4 a = Wr[t + it * 256];
        float4 b = av[t + it * 256];
        acc += a.x * b.x + a.y * b.y + a.z * b.z + a.w * b.w;
    }
    acc = wave_red_sum(acc);
    __shared__ float red[4];
    if ((t & 63) == 0) red[t >> 6] = acc;
    __syncthreads();
    if (t == 0) out[r] = hidden[r] + red[0] + red[1] + red[2] + red[3];
}

extern "C" void kernel_launch(void* const* d_in, const int* in_sizes, int n_in,
                              void* d_out, int out_size, void* d_ws, size_t ws_size,
                              hipStream_t stream) {
    const float* x        = (const float*)d_in[0];   // hidden_conv (4096)
    const float* cosv     = (const float*)d_in[1];   // (128)
    const float* sinv     = (const float*)d_in[2];   // (128)
    const float* mask     = (const float*)d_in[3];   // (8192)
    const int*   pos      = (const int*)  d_in[4];   // (1)
    float*       kv_cache = (float*)      d_in[5];   // (2,8,8192,128) — scatter target
    const float* Wq       = (const float*)d_in[6];
    const float* Wk       = (const float*)d_in[7];
    const float* Wv       = (const float*)d_in[8];
    const float* Wo       = (const float*)d_in[9];
    const float* Wgu      = (const float*)d_in[10];
    const float* Wd       = (const float*)d_in[11];
    const float* in_ln_w  = (const float*)d_in[12];
    const float* post_ln_w= (const float*)d_in[13];
    const float* q_norm_w = (const float*)d_in[14];
    const float* k_norm_w = (const float*)d_in[15];
    float* out = (float*)d_out;

    float* ws = (float*)d_ws;
    float* h        = ws;            // 4096
    float* q        = ws + 4096;     // 4096
    float* kn       = ws + 8192;     // 1024
    float* vn       = ws + 9216;     // 1024
    float* attn_out = ws + 10240;    // 4096
    float* hidden   = ws + 14336;    // 4096
    float* h2       = ws + 18432;    // 4096
    float* act      = ws + 22528;    // 12288
    float* part_m   = ws + 34816;    // 8*128*4 = 4096
    float* part_l   = ws + 38912;    // 4096
    float* part_o   = ws + 43008;    // 4096*128 = 524288 floats (2 MB)

    rmsnorm_k<<<1, 1024, 0, stream>>>(x, in_ln_w, h);
    qkv_k<<<H * D + 2 * HKV * D, 256, 0, stream>>>(Wq, Wk, Wv, h, q, kn, vn);
    norm_rope_k<<<H + HKV, 128, 0, stream>>>(q, kn, vn, q_norm_w, k_norm_w,
                                             cosv, sinv, pos, kv_cache);
    attn_split_k<<<HKV * NCHUNK, 256, 0, stream>>>(q, kv_cache, mask,
                                                   part_m, part_l, part_o);
    attn_combine_k<<<H, 128, 0, stream>>>(part_m, part_l, part_o, attn_out);
    gemv_wo_k<<<HID, 256, 0, stream>>>(Wo, attn_out, x, hidden);
    rmsnorm_k<<<1, 1024, 0, stream>>>(hidden, post_ln_w, h2);
    gemv_gu_k<<<INTD, 256, 0, stream>>>(Wgu, h2, act);
    gemv_wd_k<<<HID, 256, 0, stream>>>(Wd, act, hidden, out);
}